// Round 3
// baseline (2087.979 us; speedup 1.0000x reference)
//
#include <hip/hip_runtime.h>
#include <math.h>

// Problem constants
#define BATCH 32768
#define EMB   2048
#define KDIM  320      // 5*8*8
#define KACT  103      // ceil(0.05*2048)

// GEMM tiling (r3): 1024 threads, BM=8 rows x 2048 cols, 2 cols/thread.
// acc[8][2] = 16 VGPRs. Rationale: with BM=16 the epilogue bisection had
// 54 concurrent live regs under the 64-cap -> allocator remat'd the row
// values from LDS on every one of 32 bisection steps (r1/r2 both ~100us
// epilogue, VGPR_Count pinned at 32). BM=8 lets ALL accumulators die into
// LDS before the search: live = v[32] + misc ~= 40 < 64 -> true register
// residency. Main loop loses ~10% FMA density (16 FMA per B-load vs 32) --
// a deliberate trade.
#define BM 8
#define GTHREADS 1024
#define CIMG 8         // conv tile == A-tile

typedef unsigned uint32x4 __attribute__((ext_vector_type(4)));

// ---------------------------------------------------------------------------
// Kernel 0: transpose fc_w (2048 x 320) -> WT (320 x 2048).  (unchanged)
// ---------------------------------------------------------------------------
__global__ __launch_bounds__(256) void transpose_w_kernel(const float* __restrict__ W,
                                                          float* __restrict__ WT) {
  __shared__ float tile[32][33];
  const int k0 = blockIdx.x * 32;
  const int n0 = blockIdx.y * 32;
  const int tx = threadIdx.x;
  const int ty = threadIdx.y;
  for (int i = ty; i < 32; i += 8)
    tile[i][tx] = W[(size_t)(n0 + i) * KDIM + k0 + tx];
  __syncthreads();
  for (int i = ty; i < 32; i += 8)
    WT[(size_t)(k0 + i) * EMB + n0 + tx] = tile[tx][i];
}

// ---------------------------------------------------------------------------
// Fused kernel, BM=8:
//   phase 0: stage 8 images to LDS
//   phase 1: conv3x3+BN+ReLU+pool, waves 0..7 (one image/wave), registers ->
//            DIRECT global stores into the tile-major A-tile (no hs staging)
//   phase 2: GEMM: A via uniform s_load (SGPRs), B float2 from L2,
//            bit-identical serial-k FMA chains -> acc[8][2]
//   phase 3: order-map acc ONCE, store mapped uints to swizzled zb (64 KB)
//   phase 4: waves 0..7: register-resident 32-step MSB bisection on 32
//            values/lane (8 x ds_read_b128, conflict-free XOR chunk swizzle)
//            -> exact 103rd-largest mapped key per row
//   phase 5: re-read mapped values, u >= T -> 1.0/0.0  (== z >= topv[:,-1])
// LDS: 64 KB zb (aliases 25 KB xs) -> 2 blocks/CU, 8 waves/SIMD.
// ---------------------------------------------------------------------------
__global__ __launch_bounds__(GTHREADS, 8) void fused_conv_gemm_topk(
    const float* __restrict__ x,
    const float* __restrict__ cw,
    const float* __restrict__ gamma,
    const float* __restrict__ beta,
    const float* __restrict__ mean,
    const float* __restrict__ var,
    float* __restrict__ HtW,            // A-tile write path
    const float* __restrict__ HtR,      // A-tile read path (same memory, fenced)
    const float* __restrict__ WT,
    float* __restrict__ out) {
#pragma clang fp contract(off)
  __shared__ __attribute__((aligned(16))) unsigned smem[BM * EMB];  // 64 KB
  __shared__ float wv[45];
  __shared__ float inv_s[5], mu_s[5], be_s[5];
  __shared__ unsigned thr_s[BM];

  float* const xs = (float*)smem;      // 8*784 = 6272 floats (conv phase)
  unsigned* const zb = smem;           // 8 rows x 2048 mapped uints (epilogue)

  const int t    = threadIdx.x;
  const int lane = t & 63;
  const int w    = t >> 6;             // wave 0..15
  const int b0   = blockIdx.x * CIMG;

  // ==== phase 0: stage 8 images ===========================================
  {
    const float4* src = (const float4*)(x + (size_t)b0 * 784);
    float4* dst = (float4*)xs;
    for (int i = t; i < CIMG * 196; i += GTHREADS) dst[i] = src[i];
  }
  if (t < 45) wv[t] = cw[t];
  if (t < 5) {
    inv_s[t] = gamma[t] / sqrtf(var[t] + 1e-5f);  // IEEE div & sqrt
    mu_s[t] = mean[t];
    be_s[t] = beta[t];
  }
  __syncthreads();

  // ==== phase 1: conv+bn+relu+pool, direct A-tile stores ==================
  if (w < CIMG) {
    const int img = w;                  // one image per wave
    const float* xb = xs + img * 784;
    const int py = lane >> 3;
    const int px = lane & 7;

    float xr[5][5];
#pragma unroll
    for (int i = 0; i < 5; ++i)
#pragma unroll
      for (int j = 0; j < 5; ++j)
        xr[i][j] = xb[(3 * py + i) * 28 + 3 * px + j];

    float* dst = HtW + (size_t)blockIdx.x * (KDIM * BM);
#pragma unroll
    for (int c = 0; c < 5; ++c) {
      float wr[9];
#pragma unroll
      for (int i = 0; i < 9; ++i) wr[i] = wv[c * 9 + i];
      const float inv = inv_s[c], mu = mu_s[c], be = be_s[c];
      float mx = -__builtin_huge_valf();
#pragma unroll
      for (int ry = 0; ry < 3; ++ry)
#pragma unroll
        for (int rx = 0; rx < 3; ++rx) {
          float s = 0.0f;
#pragma unroll
          for (int di = 0; di < 3; ++di)
#pragma unroll
            for (int dj = 0; dj < 3; ++dj)
              s = __builtin_fmaf(xr[ry + di][rx + dj], wr[di * 3 + dj], s);
          float t1 = s - mu;
          float t2 = t1 * inv;
          float t3 = t2 + be;
          mx = fmaxf(mx, t3);
        }
      // A(k,m) = Ht[blk*2560 + k*8 + m],  k = c*64+lane, m = img
      dst[(c * 64 + lane) * BM + img] = fmaxf(mx, 0.0f);
    }
  }
  __syncthreads();   // drains vmcnt -> A-tile visible in L2 for s_loads

  // ==== phase 2: GEMM main loop (bit-identical FMA chains) ================
  const int m0 = blockIdx.x * BM;
  const int nt = t * 2;

  float acc[BM][2];
#pragma unroll
  for (int m = 0; m < BM; ++m) {
    acc[m][0] = 0.0f;
    acc[m][1] = 0.0f;
  }

  const float* Ap = HtR + (size_t)blockIdx.x * (KDIM * BM);  // A(k,m)=Ap[k*8+m]
  const float* wp = WT + nt;

#pragma unroll 4
  for (int k = 0; k < KDIM; ++k) {
    const float* ak = Ap + (size_t)k * BM;
    float av[BM];
#pragma unroll
    for (int m = 0; m < BM; ++m) av[m] = ak[m];   // uniform -> s_load (SGPRs)
    const float2 bb = *(const float2*)(wp + (size_t)k * EMB);
#pragma unroll
    for (int m = 0; m < BM; ++m) {
      acc[m][0] = __builtin_fmaf(av[m], bb.x, acc[m][0]);
      acc[m][1] = __builtin_fmaf(av[m], bb.y, acc[m][1]);
    }
  }

  // ==== phase 3: order-map once, store mapped keys to swizzled zb =========
  // chunk c = col>>2 (16B chunks, 512/row); swz(c) = c ^ ((c>>3)&7) --
  // bijective involution, conflict-free on both the float2-grain writes and
  // the b128 lane-contiguous reads (verified 0-conflict in r2).
  const int cW  = t >> 1;
  const int cWs = cW ^ ((cW >> 3) & 7);
  char* const zbase = (char*)zb;
  char* const wbase = zbase + (size_t)cWs * 16 + (size_t)(t & 1) * 8;

#pragma unroll
  for (int m = 0; m < BM; ++m) {
    unsigned ux = __float_as_uint(acc[m][0]);
    unsigned uy = __float_as_uint(acc[m][1]);
    uint2 u;
    u.x = ux ^ (unsigned)(((int)ux >> 31) | 0x80000000);   // ascending map
    u.y = uy ^ (unsigned)(((int)uy >> 31) | 0x80000000);
    *(uint2*)(wbase + (size_t)m * 8192) = u;
  }
  __syncthreads();

  // ==== phase 4: register-resident exact bisection, wave w -> row w =======
  if (w < BM) {
    const char* rowb = zbase + (size_t)w * 8192;
    unsigned v[32];
#pragma unroll
    for (int j = 0; j < 8; ++j) {
      const int c  = (lane << 3) | j;
      const int cs = c ^ (lane & 7);          // (c>>3)&7 == lane&7
      const uint32x4 u = *(const uint32x4*)(rowb + (size_t)cs * 16);
      v[j * 4 + 0] = u[0];
      v[j * 4 + 1] = u[1];
      v[j * 4 + 2] = u[2];
      v[j * 4 + 3] = u[3];
    }
#pragma unroll
    for (int j = 0; j < 32; ++j) asm volatile("" : "+v"(v[j]));  // pin live
    unsigned T = 0u;
    for (int b = 31; b >= 0; --b) {
      const unsigned cand = T | (1u << b);
      unsigned cnt = 0u;
#pragma unroll
      for (int j = 0; j < 32; ++j)
        cnt += (unsigned)__popcll(__ballot(v[j] >= cand));
      if (cnt >= KACT) T = cand;              // wave-uniform (SGPR) update
    }
    if (lane == 0) thr_s[w] = T;              // threshold for row m0 + w
  }
  __syncthreads();

  // ==== phase 5: binary output ============================================
#pragma unroll
  for (int m = 0; m < BM; ++m) {
    const uint2 u = *(const uint2*)(wbase + (size_t)m * 8192);
    const unsigned thr = thr_s[m];
    float2 o;
    o.x = (u.x >= thr) ? 1.0f : 0.0f;         // tie semantics: z >= topv[:,-1]
    o.y = (u.y >= thr) ? 1.0f : 0.0f;
    *(float2*)(out + (size_t)(m0 + m) * EMB + nt) = o;
  }
}

// ---------------------------------------------------------------------------
extern "C" void kernel_launch(void* const* d_in, const int* in_sizes, int n_in,
                              void* d_out, int out_size, void* d_ws, size_t ws_size,
                              hipStream_t stream) {
  const float* x      = (const float*)d_in[0];
  const float* conv_w = (const float*)d_in[1];
  const float* gamma  = (const float*)d_in[2];
  const float* beta   = (const float*)d_in[3];
  const float* mean   = (const float*)d_in[4];
  const float* var    = (const float*)d_in[5];
  const float* fc_w   = (const float*)d_in[6];
  float* out = (float*)d_out;

  // workspace: Ht tile-major (4096 tiles x 320 x 8 f32 = 40 MB) | WT (320x2048)
  float* Ht = (float*)d_ws;
  float* WT = (float*)d_ws + (size_t)KDIM * BATCH;

  transpose_w_kernel<<<dim3(KDIM / 32, EMB / 32), dim3(32, 8), 0, stream>>>(fc_w, WT);
  fused_conv_gemm_topk<<<BATCH / CIMG, GTHREADS, 0, stream>>>(
      x, conv_w, gamma, beta, mean, var, Ht, Ht, WT, out);
}

// Round 5
// 864.261 us; speedup vs baseline: 2.4159x; 2.4159x over previous
//
#include <hip/hip_runtime.h>
#include <math.h>

// Problem constants
#define BATCH 32768
#define EMB   2048
#define KDIM  320      // 5*8*8
#define KACT  103      // ceil(0.05*2048)

// GEMM tiling: 1024 threads, 16 rows x 2048 cols per block, 2 cols/thread.
// acc[16][2]=32 VGPRs, A via uniform s_load (SGPRs), 8 waves/SIMD.
// r3 lesson: BM=8 (16 FMA/B-load) is latency-catastrophic (27.9% VALUBusy,
// 1983us). BM=16 main loop is load-bearing -- do not touch.
#define BM 16
#define GTHREADS 1024
#define CIMG 16

typedef unsigned uint32x4 __attribute__((ext_vector_type(4)));

// ---------------------------------------------------------------------------
// Kernel 0: transpose fc_w (2048 x 320) -> WT (320 x 2048).  (unchanged)
// ---------------------------------------------------------------------------
__global__ __launch_bounds__(256) void transpose_w_kernel(const float* __restrict__ W,
                                                          float* __restrict__ WT) {
  __shared__ float tile[32][33];
  const int k0 = blockIdx.x * 32;
  const int n0 = blockIdx.y * 32;
  const int tx = threadIdx.x;
  const int ty = threadIdx.y;
  for (int i = ty; i < 32; i += 8)
    tile[i][tx] = W[(size_t)(n0 + i) * KDIM + k0 + tx];
  __syncthreads();
  for (int i = ty; i < 32; i += 8)
    WT[(size_t)(k0 + i) * EMB + n0 + tx] = tile[tx][i];
}

// ---------------------------------------------------------------------------
// Fused kernel (r4 resubmit): r2's verified conv + GEMM structure, LDS-free
// epilogue routed through the out buffer.
//
// Epilogue history: r1/r2 proved that under the 64-VGPR cap the allocator
// ALWAYS remats LDS-sourced bisection values on each of the 32 search steps
// (VGPR_Count pinned at 32, ~100us wasted in LDS re-reads). r3 proved the
// main loop cannot shrink to free registers. Resolution: route z through the
// OUT buffer instead of LDS --
//   ep1: all threads store mapped-uint z to out rows (coalesced float2);
//        every acc register dies here.
//   ep2: __syncthreads() -- compiler drains vmcnt before s_barrier, stores
//        are in L2; out lines were never vector-read earlier => no stale L1.
//   ep3: wave w re-reads row m0+w coalesced (8 x uint4, lanes contiguous =
//        1KB/instr, L2-hot), bisects 32 steps with q[32] in registers
//        (global loads are not remat candidates; acc dead => ~40 live < 64),
//        then writes the binary row DIRECTLY from registers (8 x float4).
// No epilogue LDS, no thr_s, no second read pass, one barrier total.
// T = max{T : count(u>=T) >= 103} = exact 103rd-largest mapped key;
// (u >= T) == reference tie semantics (z >= topv[:,-1]).
// ---------------------------------------------------------------------------
__global__ __launch_bounds__(GTHREADS, 8) void fused_conv_gemm_topk(
    const float* __restrict__ x,
    const float* __restrict__ cw,
    const float* __restrict__ gamma,
    const float* __restrict__ beta,
    const float* __restrict__ mean,
    const float* __restrict__ var,
    float* __restrict__ HtW,            // A-tile write path
    const float* __restrict__ HtR,      // A-tile read path (same memory, fenced)
    const float* __restrict__ WT,
    float* __restrict__ out) {
#pragma clang fp contract(off)
  __shared__ __attribute__((aligned(16))) float smem[17984];  // xs 12544 | hs 5440
  __shared__ float wv[45];
  __shared__ float inv_s[5], mu_s[5], be_s[5];

  float* const xs = smem;              // 16 imgs x 784
  float* const hs = smem + 12544;      // 320 x 17 k-major staging

  const int t    = threadIdx.x;
  const int lane = t & 63;
  const int w    = t >> 6;             // wave 0..15
  const int b0   = blockIdx.x * CIMG;

  // ==== phase 0: stage 16 images ==========================================
  {
    const float4* src = (const float4*)(x + (size_t)b0 * 784);
    float4* dst = (float4*)xs;
    for (int i = t; i < CIMG * 196; i += GTHREADS) dst[i] = src[i];
  }
  if (t < 45) wv[t] = cw[t];
  if (t < 5) {
    inv_s[t] = gamma[t] / sqrtf(var[t] + 1e-5f);  // IEEE div & sqrt
    mu_s[t] = mean[t];
    be_s[t] = beta[t];
  }
  __syncthreads();

  // ==== phase 1: conv+bn+relu+pool, one image per wave ====================
  {
    const int img = w;
    const float* xb = xs + img * 784;
    const int py = lane >> 3;
    const int px = lane & 7;

    float xr[5][5];
#pragma unroll
    for (int i = 0; i < 5; ++i)
#pragma unroll
      for (int j = 0; j < 5; ++j)
        xr[i][j] = xb[(3 * py + i) * 28 + 3 * px + j];

#pragma unroll
    for (int c = 0; c < 5; ++c) {
      float wr[9];
#pragma unroll
      for (int i = 0; i < 9; ++i) wr[i] = wv[c * 9 + i];
      const float inv = inv_s[c], mu = mu_s[c], be = be_s[c];
      float mx = -__builtin_huge_valf();
#pragma unroll
      for (int ry = 0; ry < 3; ++ry)
#pragma unroll
        for (int rx = 0; rx < 3; ++rx) {
          float s = 0.0f;
#pragma unroll
          for (int di = 0; di < 3; ++di)
#pragma unroll
            for (int dj = 0; dj < 3; ++dj)
              s = __builtin_fmaf(xr[ry + di][rx + dj], wr[di * 3 + dj], s);
          float t1 = s - mu;
          float t2 = t1 * inv;
          float t3 = t2 + be;
          mx = fmaxf(mx, t3);
        }
      hs[(c * 64 + lane) * 17 + img] = fmaxf(mx, 0.0f);
    }
  }
  __syncthreads();

  // ==== phase 2: A-tile -> global (coalesced; stays L2-hot) ===============
  {
    float* dst = HtW + (size_t)blockIdx.x * (KDIM * CIMG);
    for (int i = t; i < KDIM * CIMG; i += GTHREADS) {
      const int k = i >> 4;
      const int img = i & 15;
      dst[i] = hs[k * 17 + img];
    }
  }
  __syncthreads();   // drains vmcnt -> A-tile visible in L2 for s_loads

  // ==== phase 3: GEMM main loop (bit-identical to r0/r2) ==================
  const int m0 = blockIdx.x * BM;
  const int nt = t * 2;

  float acc[BM][2];
#pragma unroll
  for (int m = 0; m < BM; ++m) {
    acc[m][0] = 0.0f;
    acc[m][1] = 0.0f;
  }

  const float* Ap = HtR + (size_t)blockIdx.x * (KDIM * BM);  // A(k,m)=Ap[k*16+m]
  const float* wp = WT + nt;

#pragma unroll 4
  for (int k = 0; k < KDIM; ++k) {
    const float* ak = Ap + (size_t)k * BM;
    float av[BM];
#pragma unroll
    for (int m = 0; m < BM; ++m) av[m] = ak[m];   // uniform -> s_load (SGPRs)
    const float2 bb = *(const float2*)(wp + (size_t)k * EMB);
#pragma unroll
    for (int m = 0; m < BM; ++m) {
      acc[m][0] = __builtin_fmaf(av[m], bb.x, acc[m][0]);
      acc[m][1] = __builtin_fmaf(av[m], bb.y, acc[m][1]);
    }
  }

  // ==== ep1: store mapped-uint z into out rows (acc dies) =================
#pragma unroll
  for (int m = 0; m < BM; ++m) {
    unsigned ux = __float_as_uint(acc[m][0]);
    unsigned uy = __float_as_uint(acc[m][1]);
    uint2 u;
    u.x = ux ^ (unsigned)(((int)ux >> 31) | 0x80000000);   // ascending order map
    u.y = uy ^ (unsigned)(((int)uy >> 31) | 0x80000000);
    *(uint2*)(out + (size_t)(m0 + m) * EMB + nt) = u;
  }
  __syncthreads();   // vmcnt drained -> z rows visible in L2

  // ==== ep2: wave w owns row m0+w: coalesced re-read, bisect, write =======
  {
    const unsigned* rowp = (const unsigned*)(out + (size_t)(m0 + w) * EMB);
    uint32x4 q[8];
#pragma unroll
    for (int j = 0; j < 8; ++j)
      q[j] = *(const uint32x4*)(rowp + j * 256 + lane * 4);  // 1KB/instr coalesced
#pragma unroll
    for (int j = 0; j < 8; ++j) asm volatile("" : "+v"(q[j]));

    unsigned T = 0u;
    for (int b = 31; b >= 0; --b) {
      const unsigned cand = T | (1u << b);
      unsigned cnt = 0u;
#pragma unroll
      for (int j = 0; j < 8; ++j) {
        cnt += (unsigned)__popcll(__ballot(q[j][0] >= cand));
        cnt += (unsigned)__popcll(__ballot(q[j][1] >= cand));
        cnt += (unsigned)__popcll(__ballot(q[j][2] >= cand));
        cnt += (unsigned)__popcll(__ballot(q[j][3] >= cand));
      }
      if (cnt >= KACT) T = cand;          // wave-uniform (SGPR) update
    }

    float* rowo = out + (size_t)(m0 + w) * EMB;
#pragma unroll
    for (int j = 0; j < 8; ++j) {
      float4 o;
      o.x = (q[j][0] >= T) ? 1.0f : 0.0f;  // tie semantics: z >= topv[:,-1]
      o.y = (q[j][1] >= T) ? 1.0f : 0.0f;
      o.z = (q[j][2] >= T) ? 1.0f : 0.0f;
      o.w = (q[j][3] >= T) ? 1.0f : 0.0f;
      *(float4*)(rowo + j * 256 + lane * 4) = o;
    }
  }
}

// ---------------------------------------------------------------------------
extern "C" void kernel_launch(void* const* d_in, const int* in_sizes, int n_in,
                              void* d_out, int out_size, void* d_ws, size_t ws_size,
                              hipStream_t stream) {
  const float* x      = (const float*)d_in[0];
  const float* conv_w = (const float*)d_in[1];
  const float* gamma  = (const float*)d_in[2];
  const float* beta   = (const float*)d_in[3];
  const float* mean   = (const float*)d_in[4];
  const float* var    = (const float*)d_in[5];
  const float* fc_w   = (const float*)d_in[6];
  float* out = (float*)d_out;

  // workspace: Ht tile-major (2048 tiles x 320 x 16 f32 = 40 MB) | WT (320x2048)
  float* Ht = (float*)d_ws;
  float* WT = (float*)d_ws + (size_t)KDIM * BATCH;

  transpose_w_kernel<<<dim3(KDIM / 32, EMB / 32), dim3(32, 8), 0, stream>>>(fc_w, WT);
  fused_conv_gemm_topk<<<BATCH / CIMG, GTHREADS, 0, stream>>>(
      x, conv_w, gamma, beta, mean, var, Ht, Ht, WT, out);
}

// Round 6
// 804.652 us; speedup vs baseline: 2.5949x; 1.0741x over previous
//
#include <hip/hip_runtime.h>
#include <math.h>

// Problem constants
#define BATCH 32768
#define EMB   2048
#define KDIM  320      // 5*8*8
#define KACT  103      // ceil(0.05*2048)

// GEMM tiling: 1024 threads, 16 rows x 2048 cols per block, 2 cols/thread.
// acc[16][2]=32 VGPRs, A via uniform s_load (SGPRs), 8 waves/SIMD.
// r3 lesson: BM=8 main loop is latency-catastrophic (27.9% VALUBusy). Do not
// shrink. Session-header lesson: no manual B prefetch (reg cap). Do not touch.
#define BM 16
#define GTHREADS 1024
#define CIMG 16

// Radix histogram row stride (16B-aligned, != 0 mod 32 banks)
#define HSTRIDE 260

// ---------------------------------------------------------------------------
// Kernel 0: transpose fc_w (2048 x 320) -> WT (320 x 2048).  (unchanged)
// ---------------------------------------------------------------------------
__global__ __launch_bounds__(256) void transpose_w_kernel(const float* __restrict__ W,
                                                          float* __restrict__ WT) {
  __shared__ float tile[32][33];
  const int k0 = blockIdx.x * 32;
  const int n0 = blockIdx.y * 32;
  const int tx = threadIdx.x;
  const int ty = threadIdx.y;
  for (int i = ty; i < 32; i += 8)
    tile[i][tx] = W[(size_t)(n0 + i) * KDIM + k0 + tx];
  __syncthreads();
  for (int i = ty; i < 32; i += 8)
    WT[(size_t)(k0 + i) * EMB + n0 + tx] = tile[tx][i];
}

// ---------------------------------------------------------------------------
// Fused kernel (r6): r2's verified conv + A-tile-through-L2 + GEMM loop,
// with the epilogue REVERTED to r0's radix-256 histogram select.
//
// Epilogue cost ledger (measured across rounds, loop ~520us + conv ~25us):
//   r0 radix-256 histogram      ~38us   <- cheapest, restored here
//   r1/r2 LDS bisection          ~87us   (allocator remats LDS reads x32 steps)
//   r5 global-bisection         ~130us   (z round-trip spills L2 -> HBM,
//                                         pollutes WT stream)
// The histogram's 2.9e7 LDS bank conflicts overlap with other waves' VALU;
// wall-time cost is far below both bisection variants. histo (16.6 KB) is
// aliased into the conv's dead xs LDS region: total footprint 72.7 KB ->
// 2 blocks/CU, 8 waves/SIMD preserved.
// ---------------------------------------------------------------------------
__global__ __launch_bounds__(GTHREADS, 8) void fused_conv_gemm_topk(
    const float* __restrict__ x,
    const float* __restrict__ cw,
    const float* __restrict__ gamma,
    const float* __restrict__ beta,
    const float* __restrict__ mean,
    const float* __restrict__ var,
    float* __restrict__ HtW,            // A-tile write path
    const float* __restrict__ HtR,      // A-tile read path (same memory, fenced)
    const float* __restrict__ WT,
    float* __restrict__ out) {
#pragma clang fp contract(off)
  __shared__ __attribute__((aligned(16))) float smem[17984];  // xs 12544 | hs 5440
  __shared__ float wv[45];
  __shared__ float inv_s[5], mu_s[5], be_s[5];
  __shared__ unsigned prefix_s[BM];
  __shared__ unsigned rank_s[BM];

  float* const xs = smem;                      // 16 imgs x 784 (conv phase)
  float* const hs = smem + 12544;              // 320 x 17 k-major staging
  unsigned* const histo = (unsigned*)smem;     // BM*HSTRIDE = 16.6 KB (epilogue)

  const int t    = threadIdx.x;
  const int lane = t & 63;
  const int w    = t >> 6;             // wave 0..15
  const int b0   = blockIdx.x * CIMG;

  // ==== phase 0: stage 16 images ==========================================
  {
    const float4* src = (const float4*)(x + (size_t)b0 * 784);
    float4* dst = (float4*)xs;
    for (int i = t; i < CIMG * 196; i += GTHREADS) dst[i] = src[i];
  }
  if (t < 45) wv[t] = cw[t];
  if (t < 5) {
    inv_s[t] = gamma[t] / sqrtf(var[t] + 1e-5f);  // IEEE div & sqrt
    mu_s[t] = mean[t];
    be_s[t] = beta[t];
  }
  __syncthreads();

  // ==== phase 1: conv+bn+relu+pool, one image per wave ====================
  {
    const int img = w;
    const float* xb = xs + img * 784;
    const int py = lane >> 3;
    const int px = lane & 7;

    float xr[5][5];
#pragma unroll
    for (int i = 0; i < 5; ++i)
#pragma unroll
      for (int j = 0; j < 5; ++j)
        xr[i][j] = xb[(3 * py + i) * 28 + 3 * px + j];

#pragma unroll
    for (int c = 0; c < 5; ++c) {
      float wr[9];
#pragma unroll
      for (int i = 0; i < 9; ++i) wr[i] = wv[c * 9 + i];
      const float inv = inv_s[c], mu = mu_s[c], be = be_s[c];
      float mx = -__builtin_huge_valf();
#pragma unroll
      for (int ry = 0; ry < 3; ++ry)
#pragma unroll
        for (int rx = 0; rx < 3; ++rx) {
          float s = 0.0f;
#pragma unroll
          for (int di = 0; di < 3; ++di)
#pragma unroll
            for (int dj = 0; dj < 3; ++dj)
              s = __builtin_fmaf(xr[ry + di][rx + dj], wr[di * 3 + dj], s);
          float t1 = s - mu;
          float t2 = t1 * inv;
          float t3 = t2 + be;
          mx = fmaxf(mx, t3);
        }
      hs[(c * 64 + lane) * 17 + img] = fmaxf(mx, 0.0f);
    }
  }
  __syncthreads();

  // ==== phase 2: A-tile -> global (coalesced; stays L2-hot) ===============
  {
    float* dst = HtW + (size_t)blockIdx.x * (KDIM * CIMG);
    for (int i = t; i < KDIM * CIMG; i += GTHREADS) {
      const int k = i >> 4;
      const int img = i & 15;
      dst[i] = hs[k * 17 + img];
    }
  }
  if (t < BM) { prefix_s[t] = 0u; rank_s[t] = KACT; }  // visible after next barrier
  __syncthreads();   // drains vmcnt -> A-tile visible in L2 for s_loads

  // ==== phase 3: GEMM main loop (bit-identical; LOAD-BEARING, untouched) ==
  const int m0 = blockIdx.x * BM;
  const int nt = t * 2;

  float acc[BM][2];
#pragma unroll
  for (int m = 0; m < BM; ++m) {
    acc[m][0] = 0.0f;
    acc[m][1] = 0.0f;
  }

  const float* Ap = HtR + (size_t)blockIdx.x * (KDIM * BM);  // A(k,m)=Ap[k*16+m]
  const float* wp = WT + nt;

#pragma unroll 4
  for (int k = 0; k < KDIM; ++k) {
    const float* ak = Ap + (size_t)k * BM;
    float av[BM];
#pragma unroll
    for (int m = 0; m < BM; ++m) av[m] = ak[m];   // uniform -> s_load (SGPRs)
    const float2 bb = *(const float2*)(wp + (size_t)k * EMB);
#pragma unroll
    for (int m = 0; m < BM; ++m) {
      acc[m][0] = __builtin_fmaf(av[m], bb.x, acc[m][0]);
      acc[m][1] = __builtin_fmaf(av[m], bb.y, acc[m][1]);
    }
  }
  __syncthreads();  // conv LDS dead; prefix/rank init visible; histo region free

  // ==== phase 4: radix-256 select of the KACT-th largest per row (r0) =====
  for (int pass = 0; pass < 4; ++pass) {
    const int shift = 24 - pass * 8;
    for (int i = t; i < BM * HSTRIDE; i += GTHREADS) histo[i] = 0u;
    unsigned pref[BM];
#pragma unroll
    for (int m = 0; m < BM; ++m) pref[m] = prefix_s[m];
    __syncthreads();
#pragma unroll
    for (int m = 0; m < BM; ++m) {
#pragma unroll
      for (int j = 0; j < 2; ++j) {
        unsigned u = __float_as_uint(acc[m][j]);
        u = (u & 0x80000000u) ? ~u : (u | 0x80000000u);  // ascending order map
        const bool in = (pass == 0) || ((u >> (shift + 8)) == pref[m]);
        if (in) atomicAdd(&histo[m * HSTRIDE + ((u >> shift) & 255u)], 1u);
      }
    }
    __syncthreads();
    // Scan: wave w handles row w. Lane l covers bins [4l,4l+4); suffix-sum =
    // counts-above. Exactly one lane satisfies the rank bracket.
    {
      const int m = w;
      const unsigned rank = rank_s[m];
      const uint4 c = *(const uint4*)(histo + m * HSTRIDE + lane * 4);
      const unsigned s = c.x + c.y + c.z + c.w;
      unsigned suf = s;
#pragma unroll
      for (int off = 1; off < 64; off <<= 1) {
        const unsigned o = __shfl_down(suf, off);
        if (lane + off < 64) suf += o;
      }
      const unsigned above = suf - s;  // counts in bins > 4*lane+3
      if (above < rank && rank <= suf) {
        unsigned bin, newr;
        if (above + c.w >= rank)                    { bin = lane * 4 + 3; newr = rank - above; }
        else if (above + c.w + c.z >= rank)         { bin = lane * 4 + 2; newr = rank - above - c.w; }
        else if (above + c.w + c.z + c.y >= rank)   { bin = lane * 4 + 1; newr = rank - above - c.w - c.z; }
        else                                        { bin = lane * 4 + 0; newr = rank - above - c.w - c.z - c.y; }
        prefix_s[m] = (prefix_s[m] << 8) | bin;
        rank_s[m] = newr;
      }
    }
    __syncthreads();
  }

  // prefix_s[m] now holds the exact uint-mapped 103rd-largest value
  unsigned thr[BM];
#pragma unroll
  for (int m = 0; m < BM; ++m) thr[m] = prefix_s[m];

#pragma unroll
  for (int m = 0; m < BM; ++m) {
    float2 o;
#pragma unroll
    for (int j = 0; j < 2; ++j) {
      unsigned u = __float_as_uint(acc[m][j]);
      u = (u & 0x80000000u) ? ~u : (u | 0x80000000u);
      ((float*)&o)[j] = (u >= thr[m]) ? 1.0f : 0.0f;  // tie semantics: z >= topv[:,-1]
    }
    *(float2*)(out + (size_t)(m0 + m) * EMB + nt) = o;
  }
}

// ---------------------------------------------------------------------------
extern "C" void kernel_launch(void* const* d_in, const int* in_sizes, int n_in,
                              void* d_out, int out_size, void* d_ws, size_t ws_size,
                              hipStream_t stream) {
  const float* x      = (const float*)d_in[0];
  const float* conv_w = (const float*)d_in[1];
  const float* gamma  = (const float*)d_in[2];
  const float* beta   = (const float*)d_in[3];
  const float* mean   = (const float*)d_in[4];
  const float* var    = (const float*)d_in[5];
  const float* fc_w   = (const float*)d_in[6];
  float* out = (float*)d_out;

  // workspace: Ht tile-major (2048 tiles x 320 x 16 f32 = 40 MB) | WT (320x2048)
  float* Ht = (float*)d_ws;
  float* WT = (float*)d_ws + (size_t)KDIM * BATCH;

  transpose_w_kernel<<<dim3(KDIM / 32, EMB / 32), dim3(32, 8), 0, stream>>>(fc_w, WT);
  fused_conv_gemm_topk<<<BATCH / CIMG, GTHREADS, 0, stream>>>(
      x, conv_w, gamma, beta, mean, var, Ht, Ht, WT, out);
}